// Round 1
// baseline (524.070 us; speedup 1.0000x reference)
//
#include <hip/hip_runtime.h>
#include <hip/hip_bf16.h>

#define N_TOK 32768
#define DIM 1024
#define OUTD 1024
#define NEXP 64

typedef __attribute__((ext_vector_type(4))) float f32x4;
typedef __attribute__((ext_vector_type(8))) short bf16x8;

__device__ __forceinline__ unsigned short f2bf(float f) {
    unsigned int u = __builtin_bit_cast(unsigned int, f);
    u += 0x7FFFu + ((u >> 16) & 1u);   // RNE
    return (unsigned short)(u >> 16);
}

// ---------------- gating: fp32 logits, per-token argmax + top2 gap ----------------
// block = 256 threads, 64 tokens/block. thread (tg,eg): tokens tg+16i, experts eg+16j.
__global__ __launch_bounds__(256) void gate_kernel(const float* __restrict__ x,
        const float* __restrict__ gw, const float* __restrict__ gb,
        int* __restrict__ sel, int* __restrict__ nflag, int* __restrict__ flags)
{
    __shared__ float xs[64][36];
    __shared__ float wsm[64][36];
    int tid = threadIdx.x;
    int t0 = blockIdx.x * 64;
    int tg = tid >> 4, eg = tid & 15;

    float acc[4][4];
#pragma unroll
    for (int i = 0; i < 4; i++)
#pragma unroll
        for (int j = 0; j < 4; j++) acc[i][j] = 0.f;

    for (int k0 = 0; k0 < DIM; k0 += 32) {
        __syncthreads();
#pragma unroll
        for (int q = 0; q < 8; q++) {
            int fid = tid + q * 256;
            int r = fid >> 5, kk = fid & 31;
            xs[r][kk]  = x[(size_t)(t0 + r) * DIM + k0 + kk];
            wsm[r][kk] = gw[(size_t)r * DIM + k0 + kk];
        }
        __syncthreads();
#pragma unroll
        for (int kk4 = 0; kk4 < 8; kk4++) {
            float4 xv[4], wv[4];
#pragma unroll
            for (int i = 0; i < 4; i++)
                xv[i] = *reinterpret_cast<const float4*>(&xs[tg + 16 * i][kk4 * 4]);
#pragma unroll
            for (int j = 0; j < 4; j++)
                wv[j] = *reinterpret_cast<const float4*>(&wsm[eg + 16 * j][kk4 * 4]);
#pragma unroll
            for (int i = 0; i < 4; i++)
#pragma unroll
                for (int j = 0; j < 4; j++) {
                    acc[i][j] = fmaf(xv[i].x, wv[j].x, acc[i][j]);
                    acc[i][j] = fmaf(xv[i].y, wv[j].y, acc[i][j]);
                    acc[i][j] = fmaf(xv[i].z, wv[j].z, acc[i][j]);
                    acc[i][j] = fmaf(xv[i].w, wv[j].w, acc[i][j]);
                }
        }
    }
#pragma unroll
    for (int j = 0; j < 4; j++) {
        float b = gb[eg + 16 * j];
#pragma unroll
        for (int i = 0; i < 4; i++) acc[i][j] += b;
    }
    // per-token top2 (tie -> smaller expert index, matching jnp.argmax-first)
#pragma unroll
    for (int i = 0; i < 4; i++) {
        float m1 = -1e30f, m2 = -1e30f; int e1 = 0;
#pragma unroll
        for (int j = 0; j < 4; j++) {
            float v = acc[i][j]; int e = eg + 16 * j;
            if (v > m1) { m2 = m1; m1 = v; e1 = e; }
            else if (v > m2) m2 = v;
        }
#pragma unroll
        for (int d = 1; d < 16; d <<= 1) {
            float om1 = __shfl_xor(m1, d, 16);
            float om2 = __shfl_xor(m2, d, 16);
            int   oe1 = __shfl_xor(e1, d, 16);
            if (om1 > m1 || (om1 == m1 && oe1 < e1)) {
                m2 = fmaxf(om2, m1); m1 = om1; e1 = oe1;
            } else {
                m2 = fmaxf(m2, om1);
            }
        }
        if (eg == 0) {
            int t = t0 + tg + 16 * i;
            sel[t] = e1;
            if (m1 - m2 < 1e-3f) {        // near-tie: re-resolve in fp64
                int idx = atomicAdd(nflag, 1);
                if (idx < 4096) flags[idx] = t;
            }
        }
    }
}

// fp64 re-resolution of flagged tokens (one wave per token)
__global__ __launch_bounds__(64) void gate_fix_kernel(const float* __restrict__ x,
        const float* __restrict__ gw, const float* __restrict__ gb,
        int* __restrict__ sel, const int* __restrict__ nflag, const int* __restrict__ flags)
{
    int n = *nflag; if (n > 4096) n = 4096;
    int b = blockIdx.x;
    if (b >= n) return;
    int t = flags[b];
    int e = threadIdx.x;
    const float* xr = x + (size_t)t * DIM;
    const float* wr = gw + (size_t)e * DIM;
    double acc = (double)gb[e];
    for (int k = 0; k < DIM; k += 4) {
        acc += (double)xr[k]   * (double)wr[k];
        acc += (double)xr[k+1] * (double)wr[k+1];
        acc += (double)xr[k+2] * (double)wr[k+2];
        acc += (double)xr[k+3] * (double)wr[k+3];
    }
    double m1 = acc; int e1 = e;
#pragma unroll
    for (int d = 1; d < 64; d <<= 1) {
        double om1 = __shfl_xor(m1, d, 64);
        int   oe1  = __shfl_xor(e1, d, 64);
        if (om1 > m1 || (om1 == m1 && oe1 < e1)) { m1 = om1; e1 = oe1; }
    }
    if (e == 0) sel[t] = e1;
}

__global__ __launch_bounds__(256) void hist_kernel(const int* __restrict__ sel,
                                                   int* __restrict__ counts)
{
    __shared__ int h[NEXP];
    int tid = threadIdx.x;
    if (tid < NEXP) h[tid] = 0;
    __syncthreads();
    int t = blockIdx.x * 256 + tid;
    atomicAdd(&h[sel[t]], 1);
    __syncthreads();
    if (tid < NEXP && h[tid]) atomicAdd(&counts[tid], h[tid]);
}

__global__ void sched_kernel(const int* __restrict__ counts, int* __restrict__ offsets,
                             int* __restrict__ schedE, int* __restrict__ schedR,
                             int* __restrict__ totalRB)
{
    if (threadIdx.x != 0) return;
    int off = 0, rb = 0;
    for (int e = 0; e < NEXP; e++) {
        int c = counts[e];
        offsets[e] = off;
        int nb = (c + 127) >> 7;
        for (int b2 = 0; b2 < nb; b2++) { schedE[rb] = e; schedR[rb] = b2 * 128; rb++; }
        off += c;
    }
    offsets[NEXP] = off;
    *totalRB = rb;
}

__global__ __launch_bounds__(256) void scatter_kernel(const int* __restrict__ sel,
        const int* __restrict__ offsets, int* __restrict__ cursor, int* __restrict__ perm)
{
    int t = blockIdx.x * 256 + threadIdx.x;
    int e = sel[t];
    int pos = offsets[e] + atomicAdd(&cursor[e], 1);
    perm[pos] = t;
}

// ---------------- grouped expert GEMM, bf16 MFMA 16x16x32, 128x128x32 tile ----------------
__global__ __launch_bounds__(256) void moe_gemm_kernel(const float* __restrict__ x,
        const float* __restrict__ ew, const float* __restrict__ eb,
        const int* __restrict__ perm, const int* __restrict__ offsets,
        const int* __restrict__ counts, const int* __restrict__ schedE,
        const int* __restrict__ schedR, const int* __restrict__ totalRB,
        float* __restrict__ out)
{
    int rb = blockIdx.x;
    if (rb >= *totalRB) return;
    int cb = blockIdx.y;
    int e = schedE[rb], r0 = schedR[rb];
    int cnt = counts[e], base = offsets[e];

    __shared__ __align__(16) unsigned short As[128][40];  // [token row][k], 80B stride
    __shared__ __align__(16) unsigned short Bs[128][40];  // [o col][k]  (W transposed)
    __shared__ int toks[128];

    int tid = threadIdx.x;
    if (tid < 128) {
        int r = r0 + tid;
        toks[tid] = (r < cnt) ? perm[base + r] : -1;
    }
    __syncthreads();

    int lane = tid & 63;
    int wave = tid >> 6;
    int wr = wave >> 1, wc = wave & 1;
    int lr = lane & 15, lg = lane >> 4;

    f32x4 acc[4][4];
#pragma unroll
    for (int m = 0; m < 4; m++)
#pragma unroll
        for (int n = 0; n < 4; n++)
#pragma unroll
            for (int c = 0; c < 4; c++) acc[m][n][c] = 0.f;

    int aRow[4]; int aTok[4];
#pragma unroll
    for (int q = 0; q < 4; q++) {
        aRow[q] = (tid >> 3) + q * 32;
        int tk = toks[aRow[q]];
        aTok[q] = (tk < 0) ? 0 : tk;
    }
    int ac4 = tid & 7;
    int d0 = (tid >> 5) * 4;
    int o_lane = tid & 31;
    const float* wb = ew + (size_t)e * (DIM * OUTD) + (size_t)cb * 128;

    for (int k0 = 0; k0 < DIM; k0 += 32) {
        // global loads to regs (A: token rows; B: 4x4 tile of W for register transpose)
        float4 av[4];
#pragma unroll
        for (int q = 0; q < 4; q++)
            av[q] = *reinterpret_cast<const float4*>(&x[(size_t)aTok[q] * DIM + k0 + ac4 * 4]);
        float bv[4][4];
#pragma unroll
        for (int i2 = 0; i2 < 4; i2++)
#pragma unroll
            for (int j = 0; j < 4; j++)
                bv[i2][j] = wb[(size_t)(k0 + d0 + i2) * OUTD + o_lane + 32 * j];

        __syncthreads();   // prev iter's LDS reads complete
#pragma unroll
        for (int q = 0; q < 4; q++) {
            uint2 p;
            p.x = (unsigned int)f2bf(av[q].x) | ((unsigned int)f2bf(av[q].y) << 16);
            p.y = (unsigned int)f2bf(av[q].z) | ((unsigned int)f2bf(av[q].w) << 16);
            *reinterpret_cast<uint2*>(&As[aRow[q]][ac4 * 4]) = p;
        }
#pragma unroll
        for (int j = 0; j < 4; j++) {
            uint2 p;
            p.x = (unsigned int)f2bf(bv[0][j]) | ((unsigned int)f2bf(bv[1][j]) << 16);
            p.y = (unsigned int)f2bf(bv[2][j]) | ((unsigned int)f2bf(bv[3][j]) << 16);
            *reinterpret_cast<uint2*>(&Bs[o_lane + 32 * j][d0]) = p;
        }
        __syncthreads();

        bf16x8 bfr[4];
#pragma unroll
        for (int n = 0; n < 4; n++)
            bfr[n] = *reinterpret_cast<const bf16x8*>(&Bs[wc * 64 + n * 16 + lr][lg * 8]);
#pragma unroll
        for (int m = 0; m < 4; m++) {
            bf16x8 afr = *reinterpret_cast<const bf16x8*>(&As[wr * 64 + m * 16 + lr][lg * 8]);
#pragma unroll
            for (int n = 0; n < 4; n++)
                acc[m][n] = __builtin_amdgcn_mfma_f32_16x16x32_bf16(afr, bfr[n], acc[m][n], 0, 0, 0);
        }
    }

    // epilogue: C/D layout col = lane&15, row = (lane>>4)*4 + i  [m89]
#pragma unroll
    for (int n = 0; n < 4; n++) {
        int oc = cb * 128 + wc * 64 + n * 16 + lr;
        float bias = eb[e * OUTD + oc];
#pragma unroll
        for (int m = 0; m < 4; m++) {
#pragma unroll
            for (int i2 = 0; i2 < 4; i2++) {
                int rr = wr * 64 + m * 16 + lg * 4 + i2;
                int tk = toks[rr];
                if (tk >= 0)
                    out[(size_t)tk * OUTD + oc] = acc[m][n][i2] + bias;
            }
        }
    }
}

extern "C" void kernel_launch(void* const* d_in, const int* in_sizes, int n_in,
                              void* d_out, int out_size, void* d_ws, size_t ws_size,
                              hipStream_t stream)
{
    const float* x  = (const float*)d_in[0];
    const float* gw = (const float*)d_in[1];
    const float* gb = (const float*)d_in[2];
    const float* ew = (const float*)d_in[3];
    const float* eb = (const float*)d_in[4];
    float* out = (float*)d_out;

    char* ws = (char*)d_ws;
    int* counts  = (int*)(ws + 0);        // 64
    int* cursor  = (int*)(ws + 256);      // 64
    int* offsets = (int*)(ws + 512);      // 65
    int* totalRB = (int*)(ws + 1024);
    int* nflag   = (int*)(ws + 1028);
    int* flags   = (int*)(ws + 1032);     // 4096
    int* schedE  = (int*)(ws + 20480);    // <=512
    int* schedR  = (int*)(ws + 22528);    // <=512
    int* perm    = (int*)(ws + 65536);    // 32768
    int* sel     = (int*)(ws + 65536 + 131072);

    hipMemsetAsync(ws, 0, 2048, stream);  // counts, cursor, totalRB, nflag

    gate_kernel<<<dim3(N_TOK / 64), 256, 0, stream>>>(x, gw, gb, sel, nflag, flags);
    gate_fix_kernel<<<dim3(4096), 64, 0, stream>>>(x, gw, gb, sel, nflag, flags);
    hist_kernel<<<dim3(N_TOK / 256), 256, 0, stream>>>(sel, counts);
    sched_kernel<<<dim3(1), 64, 0, stream>>>(counts, offsets, schedE, schedR, totalRB);
    scatter_kernel<<<dim3(N_TOK / 256), 256, 0, stream>>>(sel, offsets, cursor, perm);
    moe_gemm_kernel<<<dim3(320, 8), 256, 0, stream>>>(x, ew, eb, perm, offsets, counts,
                                                      schedE, schedR, totalRB, out);
}

// Round 2
// 480.614 us; speedup vs baseline: 1.0904x; 1.0904x over previous
//
#include <hip/hip_runtime.h>
#include <hip/hip_bf16.h>

#define N_TOK 32768
#define DIM 1024
#define OUTD 1024
#define NEXP 64

typedef __attribute__((ext_vector_type(4))) float f32x4;
typedef __attribute__((ext_vector_type(8))) short bf16x8;

__device__ __forceinline__ unsigned short f2bf(float f) {
    unsigned int u = __builtin_bit_cast(unsigned int, f);
    u += 0x7FFFu + ((u >> 16) & 1u);   // RNE
    return (unsigned short)(u >> 16);
}

#define GLOAD16(gp, lp) \
    __builtin_amdgcn_global_load_lds((const __attribute__((address_space(1))) void*)(gp), \
                                     (__attribute__((address_space(3))) void*)(lp), 16, 0, 0)

// ---------------- gating: fp32 logits, per-token argmax + top2 gap ----------------
// Also emits bf16 copy of x (xb) fused into the staging pass (x is read exactly once here).
__global__ __launch_bounds__(256) void gate_kernel(const float* __restrict__ x,
        const float* __restrict__ gw, const float* __restrict__ gb,
        int* __restrict__ sel, int* __restrict__ nflag, int* __restrict__ flags,
        unsigned short* __restrict__ xb)
{
    __shared__ float xs[64][36];
    __shared__ float wsm[64][36];
    int tid = threadIdx.x;
    int t0 = blockIdx.x * 64;
    int tg = tid >> 4, eg = tid & 15;

    float acc[4][4];
#pragma unroll
    for (int i = 0; i < 4; i++)
#pragma unroll
        for (int j = 0; j < 4; j++) acc[i][j] = 0.f;

    for (int k0 = 0; k0 < DIM; k0 += 32) {
        __syncthreads();
#pragma unroll
        for (int q = 0; q < 2; q++) {
            int cidx = tid + q * 256;            // 512 float4 chunks
            int r = cidx >> 3, c4 = (cidx & 7) * 4;
            *reinterpret_cast<float4*>(&xs[r][c4]) =
                *reinterpret_cast<const float4*>(&x[(size_t)(t0 + r) * DIM + k0 + c4]);
            *reinterpret_cast<float4*>(&wsm[r][c4]) =
                *reinterpret_cast<const float4*>(&gw[(size_t)r * DIM + k0 + c4]);
        }
        __syncthreads();
        if (xb) {   // fused x -> bf16 writeout (uniform branch)
            int r = tid >> 2, cc = (tid & 3) * 8;
            float4 v0 = *reinterpret_cast<const float4*>(&xs[r][cc]);
            float4 v1 = *reinterpret_cast<const float4*>(&xs[r][cc + 4]);
            uint4 p;
            p.x = (unsigned int)f2bf(v0.x) | ((unsigned int)f2bf(v0.y) << 16);
            p.y = (unsigned int)f2bf(v0.z) | ((unsigned int)f2bf(v0.w) << 16);
            p.z = (unsigned int)f2bf(v1.x) | ((unsigned int)f2bf(v1.y) << 16);
            p.w = (unsigned int)f2bf(v1.z) | ((unsigned int)f2bf(v1.w) << 16);
            *reinterpret_cast<uint4*>(&xb[(size_t)(t0 + r) * DIM + k0 + cc]) = p;
        }
#pragma unroll
        for (int kk4 = 0; kk4 < 8; kk4++) {
            float4 xv[4], wv[4];
#pragma unroll
            for (int i = 0; i < 4; i++)
                xv[i] = *reinterpret_cast<const float4*>(&xs[tg + 16 * i][kk4 * 4]);
#pragma unroll
            for (int j = 0; j < 4; j++)
                wv[j] = *reinterpret_cast<const float4*>(&wsm[eg + 16 * j][kk4 * 4]);
#pragma unroll
            for (int i = 0; i < 4; i++)
#pragma unroll
                for (int j = 0; j < 4; j++) {
                    acc[i][j] = fmaf(xv[i].x, wv[j].x, acc[i][j]);
                    acc[i][j] = fmaf(xv[i].y, wv[j].y, acc[i][j]);
                    acc[i][j] = fmaf(xv[i].z, wv[j].z, acc[i][j]);
                    acc[i][j] = fmaf(xv[i].w, wv[j].w, acc[i][j]);
                }
        }
    }
#pragma unroll
    for (int j = 0; j < 4; j++) {
        float b = gb[eg + 16 * j];
#pragma unroll
        for (int i = 0; i < 4; i++) acc[i][j] += b;
    }
#pragma unroll
    for (int i = 0; i < 4; i++) {
        float m1 = -1e30f, m2 = -1e30f; int e1 = 0;
#pragma unroll
        for (int j = 0; j < 4; j++) {
            float v = acc[i][j]; int e = eg + 16 * j;
            if (v > m1) { m2 = m1; m1 = v; e1 = e; }
            else if (v > m2) m2 = v;
        }
#pragma unroll
        for (int d = 1; d < 16; d <<= 1) {
            float om1 = __shfl_xor(m1, d, 16);
            float om2 = __shfl_xor(m2, d, 16);
            int   oe1 = __shfl_xor(e1, d, 16);
            if (om1 > m1 || (om1 == m1 && oe1 < e1)) {
                m2 = fmaxf(om2, m1); m1 = om1; e1 = oe1;
            } else {
                m2 = fmaxf(m2, om1);
            }
        }
        if (eg == 0) {
            int t = t0 + tg + 16 * i;
            sel[t] = e1;
            if (m1 - m2 < 1e-3f) {
                int idx = atomicAdd(nflag, 1);
                if (idx < 4096) flags[idx] = t;
            }
        }
    }
}

__global__ __launch_bounds__(64) void gate_fix_kernel(const float* __restrict__ x,
        const float* __restrict__ gw, const float* __restrict__ gb,
        int* __restrict__ sel, const int* __restrict__ nflag, const int* __restrict__ flags)
{
    int n = *nflag; if (n > 4096) n = 4096;
    int b = blockIdx.x;
    if (b >= n) return;
    int t = flags[b];
    int e = threadIdx.x;
    const float* xr = x + (size_t)t * DIM;
    const float* wr = gw + (size_t)e * DIM;
    double acc = (double)gb[e];
    for (int k = 0; k < DIM; k += 4) {
        acc += (double)xr[k]   * (double)wr[k];
        acc += (double)xr[k+1] * (double)wr[k+1];
        acc += (double)xr[k+2] * (double)wr[k+2];
        acc += (double)xr[k+3] * (double)wr[k+3];
    }
    double m1 = acc; int e1 = e;
#pragma unroll
    for (int d = 1; d < 64; d <<= 1) {
        double om1 = __shfl_xor(m1, d, 64);
        int   oe1  = __shfl_xor(e1, d, 64);
        if (om1 > m1 || (om1 == m1 && oe1 < e1)) { m1 = om1; e1 = oe1; }
    }
    if (e == 0) sel[t] = e1;
}

__global__ __launch_bounds__(256) void hist_kernel(const int* __restrict__ sel,
                                                   int* __restrict__ counts)
{
    __shared__ int h[NEXP];
    int tid = threadIdx.x;
    if (tid < NEXP) h[tid] = 0;
    __syncthreads();
    int t = blockIdx.x * 256 + tid;
    atomicAdd(&h[sel[t]], 1);
    __syncthreads();
    if (tid < NEXP && h[tid]) atomicAdd(&counts[tid], h[tid]);
}

__global__ void sched_kernel(const int* __restrict__ counts, int* __restrict__ offsets,
                             int* __restrict__ schedE, int* __restrict__ schedR,
                             int* __restrict__ totalRB)
{
    if (threadIdx.x != 0) return;
    int off = 0, rb = 0;
    for (int e = 0; e < NEXP; e++) {
        int c = counts[e];
        offsets[e] = off;
        int nb = (c + 127) >> 7;
        for (int b2 = 0; b2 < nb; b2++) { schedE[rb] = e; schedR[rb] = b2 * 128; rb++; }
        off += c;
    }
    offsets[NEXP] = off;
    *totalRB = rb;
}

__global__ __launch_bounds__(256) void scatter_kernel(const int* __restrict__ sel,
        const int* __restrict__ offsets, int* __restrict__ cursor, int* __restrict__ perm)
{
    int t = blockIdx.x * 256 + threadIdx.x;
    int e = sel[t];
    int pos = offsets[e] + atomicAdd(&cursor[e], 1);
    perm[pos] = t;
}

// ---------------- W [E][D][O] fp32 -> wt [E][O][D] bf16 ----------------
__global__ __launch_bounds__(256) void transpose_w_kernel(const float* __restrict__ ew,
                                                          unsigned short* __restrict__ wt)
{
    __shared__ unsigned short ts[64][68];
    int e = blockIdx.z;
    int d0 = blockIdx.x * 64, o0 = blockIdx.y * 64;
    int tid = threadIdx.x;
    const float* src = ew + (size_t)e * (DIM * OUTD);
    int r = tid >> 4, c = (tid & 15) * 4;
#pragma unroll
    for (int i = 0; i < 4; i++) {
        int rr = r + i * 16;
        float4 v = *reinterpret_cast<const float4*>(&src[(size_t)(d0 + rr) * OUTD + o0 + c]);
        ushort4 u;
        u.x = f2bf(v.x); u.y = f2bf(v.y); u.z = f2bf(v.z); u.w = f2bf(v.w);
        *reinterpret_cast<ushort4*>(&ts[rr][c]) = u;
    }
    __syncthreads();
    unsigned short* dst = wt + (size_t)e * (DIM * OUTD);
    int dc = tid & 7;
#pragma unroll
    for (int i = 0; i < 2; i++) {
        int oo = (tid >> 3) + i * 32;
        unsigned int w0 = 0, w1 = 0, w2 = 0, w3 = 0;
        w0 = (unsigned int)ts[dc*8+0][oo] | ((unsigned int)ts[dc*8+1][oo] << 16);
        w1 = (unsigned int)ts[dc*8+2][oo] | ((unsigned int)ts[dc*8+3][oo] << 16);
        w2 = (unsigned int)ts[dc*8+4][oo] | ((unsigned int)ts[dc*8+5][oo] << 16);
        w3 = (unsigned int)ts[dc*8+6][oo] | ((unsigned int)ts[dc*8+7][oo] << 16);
        uint4 p; p.x = w0; p.y = w1; p.z = w2; p.w = w3;
        *reinterpret_cast<uint4*>(&dst[(size_t)(o0 + oo) * DIM + d0 + dc * 8]) = p;
    }
}

// ---------------- grouped expert GEMM, m97-style, 128x128x32, bf16 MFMA ----------------
// AMODE 2: A via global_load_lds from xb.  AMODE 1: A via fp32 gather + f2bf + ds_write.
// LDS tiles linear [128 rows][32 k] bf16; k-chunk XOR-swizzle: storage chunk s holds
// global chunk s ^ ((row>>1)&3)  -> ds_read_b128 fragment reads are 2-way max (free).
template<int AMODE>
__global__ __launch_bounds__(256) void moe_gemm(const float* __restrict__ x,
        const unsigned short* __restrict__ xb, const unsigned short* __restrict__ wt,
        const float* __restrict__ eb,
        const int* __restrict__ perm, const int* __restrict__ offsets,
        const int* __restrict__ counts, const int* __restrict__ schedE,
        const int* __restrict__ schedR, const int* __restrict__ totalRB,
        float* __restrict__ out)
{
    int rb = blockIdx.x;
    if (rb >= *totalRB) return;
    int cb = blockIdx.y;
    int e = schedE[rb], r0 = schedR[rb];
    int cnt = counts[e], base = offsets[e];

    __shared__ __align__(16) unsigned short As[4096];   // 128 x 32
    __shared__ __align__(16) unsigned short Bs[4096];
    __shared__ int toks[128];

    int tid = threadIdx.x;
    if (tid < 128) {
        int r = r0 + tid;
        toks[tid] = (r < cnt) ? perm[base + r] : -1;
    }
    __syncthreads();

    int lane = tid & 63;
    int wv = tid >> 6;
    int wr = wv >> 1, wc = wv & 1;
    int lr = lane & 15, lg = lane >> 4;

    // staging geometry: chunk c = tid + i*256; row = c>>2; koff = ((c&3)^((c>>3)&3))*8
    int rowS = tid >> 2;
    int koff = (((tid & 3) ^ ((tid >> 3) & 3)) * 8);
    int tokA1 = toks[rowS];      if (tokA1 < 0) tokA1 = 0;
    int tokA2 = toks[64 + rowS]; if (tokA2 < 0) tokA2 = 0;

    const unsigned short* wte = wt + ((size_t)e << 20);
    const unsigned short* bSrc1 = wte + (size_t)(cb * 128 + rowS) * DIM + koff;
    const unsigned short* bSrc2 = wte + (size_t)(cb * 128 + 64 + rowS) * DIM + koff;

    const unsigned short* aSrc1b = (AMODE == 2) ? xb + (size_t)tokA1 * DIM + koff : nullptr;
    const unsigned short* aSrc2b = (AMODE == 2) ? xb + (size_t)tokA2 * DIM + koff : nullptr;
    const float* aSrc1f = (AMODE == 1) ? x + (size_t)tokA1 * DIM + koff : nullptr;
    const float* aSrc2f = (AMODE == 1) ? x + (size_t)tokA2 * DIM + koff : nullptr;

    // wave-uniform LDS bases for global_load_lds (lane*16B auto-appended by HW)
    unsigned short* AsW0 = As + wv * 512;            // chunks [wv*64 .. wv*64+63]
    unsigned short* AsW1 = As + 2048 + wv * 512;     // chunks [256+wv*64 ..]
    unsigned short* BsW0 = Bs + wv * 512;
    unsigned short* BsW1 = Bs + 2048 + wv * 512;

    f32x4 acc[4][4];
#pragma unroll
    for (int m = 0; m < 4; m++)
#pragma unroll
        for (int n = 0; n < 4; n++)
#pragma unroll
            for (int c = 0; c < 4; c++) acc[m][n][c] = 0.f;

    const char* Asc = (const char*)As;
    const char* Bsc = (const char*)Bs;
    int gl = (lr >> 1) & 3;                 // fragment-read swizzle key
    int fko = ((lg ^ gl) * 16);             // byte offset of k-group within row

    for (int k0 = 0; k0 < DIM; k0 += 32) {
        // ---- stage B (always direct-to-LDS) ----
        GLOAD16(bSrc1 + k0, BsW0);
        GLOAD16(bSrc2 + k0, BsW1);
        // ---- stage A ----
        if (AMODE == 2) {
            GLOAD16(aSrc1b + k0, AsW0);
            GLOAD16(aSrc2b + k0, AsW1);
        } else {
            float4 a0 = *reinterpret_cast<const float4*>(aSrc1f + k0);
            float4 a1 = *reinterpret_cast<const float4*>(aSrc1f + k0 + 4);
            uint4 p;
            p.x = (unsigned int)f2bf(a0.x) | ((unsigned int)f2bf(a0.y) << 16);
            p.y = (unsigned int)f2bf(a0.z) | ((unsigned int)f2bf(a0.w) << 16);
            p.z = (unsigned int)f2bf(a1.x) | ((unsigned int)f2bf(a1.y) << 16);
            p.w = (unsigned int)f2bf(a1.z) | ((unsigned int)f2bf(a1.w) << 16);
            *reinterpret_cast<uint4*>(&As[(size_t)tid * 8]) = p;
            float4 b0 = *reinterpret_cast<const float4*>(aSrc2f + k0);
            float4 b1 = *reinterpret_cast<const float4*>(aSrc2f + k0 + 4);
            uint4 q;
            q.x = (unsigned int)f2bf(b0.x) | ((unsigned int)f2bf(b0.y) << 16);
            q.y = (unsigned int)f2bf(b0.z) | ((unsigned int)f2bf(b0.w) << 16);
            q.z = (unsigned int)f2bf(b1.x) | ((unsigned int)f2bf(b1.y) << 16);
            q.w = (unsigned int)f2bf(b1.z) | ((unsigned int)f2bf(b1.w) << 16);
            *reinterpret_cast<uint4*>(&As[(size_t)(tid + 256) * 8]) = q;
        }
        __syncthreads();   // drains vmcnt/lgkmcnt -> tiles complete

        bf16x8 bfr[4];
#pragma unroll
        for (int n = 0; n < 4; n++) {
            int row = wc * 64 + n * 16 + lr;
            bfr[n] = *reinterpret_cast<const bf16x8*>(Bsc + (row << 6) + fko);
        }
#pragma unroll
        for (int m = 0; m < 4; m++) {
            int row = wr * 64 + m * 16 + lr;
            bf16x8 afr = *reinterpret_cast<const bf16x8*>(Asc + (row << 6) + fko);
#pragma unroll
            for (int n = 0; n < 4; n++)
                acc[m][n] = __builtin_amdgcn_mfma_f32_16x16x32_bf16(afr, bfr[n], acc[m][n], 0, 0, 0);
        }
        __syncthreads();   // all reads done -> safe to overwrite
    }

#pragma unroll
    for (int n = 0; n < 4; n++) {
        int oc = cb * 128 + wc * 64 + n * 16 + lr;
        float bias = eb[e * OUTD + oc];
#pragma unroll
        for (int m = 0; m < 4; m++) {
#pragma unroll
            for (int i2 = 0; i2 < 4; i2++) {
                int rr = wr * 64 + m * 16 + lg * 4 + i2;
                int tk = toks[rr];
                if (tk >= 0)
                    out[(size_t)tk * OUTD + oc] = acc[m][n][i2] + bias;
            }
        }
    }
}

// ---------------- legacy (R1) GEMM — fallback if ws too small for wt ----------------
__global__ __launch_bounds__(256) void moe_gemm_legacy(const float* __restrict__ x,
        const float* __restrict__ ew, const float* __restrict__ eb,
        const int* __restrict__ perm, const int* __restrict__ offsets,
        const int* __restrict__ counts, const int* __restrict__ schedE,
        const int* __restrict__ schedR, const int* __restrict__ totalRB,
        float* __restrict__ out)
{
    int rb = blockIdx.x;
    if (rb >= *totalRB) return;
    int cb = blockIdx.y;
    int e = schedE[rb], r0 = schedR[rb];
    int cnt = counts[e], base = offsets[e];

    __shared__ __align__(16) unsigned short As[128][40];
    __shared__ __align__(16) unsigned short Bs[128][40];
    __shared__ int toks[128];

    int tid = threadIdx.x;
    if (tid < 128) {
        int r = r0 + tid;
        toks[tid] = (r < cnt) ? perm[base + r] : -1;
    }
    __syncthreads();

    int lane = tid & 63;
    int wave = tid >> 6;
    int wr = wave >> 1, wc = wave & 1;
    int lr = lane & 15, lg = lane >> 4;

    f32x4 acc[4][4];
#pragma unroll
    for (int m = 0; m < 4; m++)
#pragma unroll
        for (int n = 0; n < 4; n++)
#pragma unroll
            for (int c = 0; c < 4; c++) acc[m][n][c] = 0.f;

    int aRow[4]; int aTok[4];
#pragma unroll
    for (int q = 0; q < 4; q++) {
        aRow[q] = (tid >> 3) + q * 32;
        int tk = toks[aRow[q]];
        aTok[q] = (tk < 0) ? 0 : tk;
    }
    int ac4 = tid & 7;
    int d0 = (tid >> 5) * 4;
    int o_lane = tid & 31;
    const float* wb = ew + (size_t)e * (DIM * OUTD) + (size_t)cb * 128;

    for (int k0 = 0; k0 < DIM; k0 += 32) {
        float4 av[4];
#pragma unroll
        for (int q = 0; q < 4; q++)
            av[q] = *reinterpret_cast<const float4*>(&x[(size_t)aTok[q] * DIM + k0 + ac4 * 4]);
        float bv[4][4];
#pragma unroll
        for (int i2 = 0; i2 < 4; i2++)
#pragma unroll
            for (int j = 0; j < 4; j++)
                bv[i2][j] = wb[(size_t)(k0 + d0 + i2) * OUTD + o_lane + 32 * j];

        __syncthreads();
#pragma unroll
        for (int q = 0; q < 4; q++) {
            uint2 p;
            p.x = (unsigned int)f2bf(av[q].x) | ((unsigned int)f2bf(av[q].y) << 16);
            p.y = (unsigned int)f2bf(av[q].z) | ((unsigned int)f2bf(av[q].w) << 16);
            *reinterpret_cast<uint2*>(&As[aRow[q]][ac4 * 4]) = p;
        }
#pragma unroll
        for (int j = 0; j < 4; j++) {
            uint2 p;
            p.x = (unsigned int)f2bf(bv[0][j]) | ((unsigned int)f2bf(bv[1][j]) << 16);
            p.y = (unsigned int)f2bf(bv[2][j]) | ((unsigned int)f2bf(bv[3][j]) << 16);
            *reinterpret_cast<uint2*>(&Bs[o_lane + 32 * j][d0]) = p;
        }
        __syncthreads();

        bf16x8 bfr[4];
#pragma unroll
        for (int n = 0; n < 4; n++)
            bfr[n] = *reinterpret_cast<const bf16x8*>(&Bs[wc * 64 + n * 16 + lr][lg * 8]);
#pragma unroll
        for (int m = 0; m < 4; m++) {
            bf16x8 afr = *reinterpret_cast<const bf16x8*>(&As[wr * 64 + m * 16 + lr][lg * 8]);
#pragma unroll
            for (int n = 0; n < 4; n++)
                acc[m][n] = __builtin_amdgcn_mfma_f32_16x16x32_bf16(afr, bfr[n], acc[m][n], 0, 0, 0);
        }
    }

#pragma unroll
    for (int n = 0; n < 4; n++) {
        int oc = cb * 128 + wc * 64 + n * 16 + lr;
        float bias = eb[e * OUTD + oc];
#pragma unroll
        for (int m = 0; m < 4; m++) {
#pragma unroll
            for (int i2 = 0; i2 < 4; i2++) {
                int rr = wr * 64 + m * 16 + lg * 4 + i2;
                int tk = toks[rr];
                if (tk >= 0)
                    out[(size_t)tk * OUTD + oc] = acc[m][n][i2] + bias;
            }
        }
    }
}

extern "C" void kernel_launch(void* const* d_in, const int* in_sizes, int n_in,
                              void* d_out, int out_size, void* d_ws, size_t ws_size,
                              hipStream_t stream)
{
    const float* x  = (const float*)d_in[0];
    const float* gw = (const float*)d_in[1];
    const float* gb = (const float*)d_in[2];
    const float* ew = (const float*)d_in[3];
    const float* eb = (const float*)d_in[4];
    float* out = (float*)d_out;

    char* ws = (char*)d_ws;
    int* counts  = (int*)(ws + 0);
    int* cursor  = (int*)(ws + 256);
    int* offsets = (int*)(ws + 512);
    int* totalRB = (int*)(ws + 1024);
    int* nflag   = (int*)(ws + 1028);
    int* flags   = (int*)(ws + 1032);
    int* schedE  = (int*)(ws + 20480);
    int* schedR  = (int*)(ws + 22528);
    int* sel     = (int*)(ws + 24576);
    int* perm    = (int*)(ws + 155648);

    const size_t WT_OFF   = (size_t)1 << 20;
    const size_t WT_BYTES = (size_t)NEXP * DIM * OUTD * 2;   // 134,217,728
    const size_t XB_OFF   = WT_OFF + WT_BYTES;
    const size_t XB_BYTES = (size_t)N_TOK * DIM * 2;         // 67,108,864
    int mode = (ws_size >= XB_OFF + XB_BYTES) ? 2
             : (ws_size >= WT_OFF + WT_BYTES) ? 1 : 0;
    unsigned short* wt = (mode >= 1) ? (unsigned short*)(ws + WT_OFF) : nullptr;
    unsigned short* xb = (mode == 2) ? (unsigned short*)(ws + XB_OFF) : nullptr;

    hipMemsetAsync(ws, 0, 2048, stream);

    gate_kernel<<<dim3(N_TOK / 64), 256, 0, stream>>>(x, gw, gb, sel, nflag, flags, xb);
    gate_fix_kernel<<<dim3(4096), 64, 0, stream>>>(x, gw, gb, sel, nflag, flags);
    hist_kernel<<<dim3(N_TOK / 256), 256, 0, stream>>>(sel, counts);
    sched_kernel<<<dim3(1), 64, 0, stream>>>(counts, offsets, schedE, schedR, totalRB);
    scatter_kernel<<<dim3(N_TOK / 256), 256, 0, stream>>>(sel, offsets, cursor, perm);
    if (mode >= 1)
        transpose_w_kernel<<<dim3(16, 16, 64), 256, 0, stream>>>(ew, wt);

    if (mode == 2)
        moe_gemm<2><<<dim3(320, 8), 256, 0, stream>>>(x, xb, wt, eb, perm, offsets, counts,
                                                      schedE, schedR, totalRB, out);
    else if (mode == 1)
        moe_gemm<1><<<dim3(320, 8), 256, 0, stream>>>(x, xb, wt, eb, perm, offsets, counts,
                                                      schedE, schedR, totalRB, out);
    else
        moe_gemm_legacy<<<dim3(320, 8), 256, 0, stream>>>(x, ew, eb, perm, offsets, counts,
                                                          schedE, schedR, totalRB, out);
}

// Round 3
// 445.849 us; speedup vs baseline: 1.1754x; 1.0780x over previous
//
#include <hip/hip_runtime.h>
#include <hip/hip_bf16.h>

#define N_TOK 32768
#define DIM 1024
#define OUTD 1024
#define NEXP 64

typedef __attribute__((ext_vector_type(4))) float f32x4;
typedef __attribute__((ext_vector_type(8))) short bf16x8;

__device__ __forceinline__ unsigned short f2bf(float f) {
    unsigned int u = __builtin_bit_cast(unsigned int, f);
    u += 0x7FFFu + ((u >> 16) & 1u);   // RNE
    return (unsigned short)(u >> 16);
}

#define GLOAD16(gp, lp) \
    __builtin_amdgcn_global_load_lds((const __attribute__((address_space(1))) void*)(gp), \
                                     (__attribute__((address_space(3))) void*)(lp), 16, 0, 0)

// ---------------- prep: gate (blocks 0..511) + W transpose (blocks 512..16895) ----------------
// gate: fp32 logits, per-token argmax + top2 gap; fused x->bf16 (xb) writeout.
// transpose: W [E][D][O] fp32 -> wt [E][O][D] bf16.
__global__ __launch_bounds__(256) void prep_kernel(const float* __restrict__ x,
        const float* __restrict__ gw, const float* __restrict__ gb,
        const float* __restrict__ ew,
        int* __restrict__ sel, int* __restrict__ nflag, int* __restrict__ flags,
        unsigned short* __restrict__ xb, unsigned short* __restrict__ wt)
{
    __shared__ __align__(16) char smem[18432];
    int tid = threadIdx.x;

    if (blockIdx.x < 512) {
        // ---------------- gate ----------------
        float (*xs)[36]  = (float(*)[36])smem;
        float (*wsm)[36] = (float(*)[36])(smem + 9216);
        int t0 = blockIdx.x * 64;
        int tg = tid >> 4, eg = tid & 15;

        float acc[4][4];
#pragma unroll
        for (int i = 0; i < 4; i++)
#pragma unroll
            for (int j = 0; j < 4; j++) acc[i][j] = 0.f;

        for (int k0 = 0; k0 < DIM; k0 += 32) {
            __syncthreads();
#pragma unroll
            for (int q = 0; q < 2; q++) {
                int cidx = tid + q * 256;
                int r = cidx >> 3, c4 = (cidx & 7) * 4;
                *reinterpret_cast<float4*>(&xs[r][c4]) =
                    *reinterpret_cast<const float4*>(&x[(size_t)(t0 + r) * DIM + k0 + c4]);
                *reinterpret_cast<float4*>(&wsm[r][c4]) =
                    *reinterpret_cast<const float4*>(&gw[(size_t)r * DIM + k0 + c4]);
            }
            __syncthreads();
            if (xb) {
                int r = tid >> 2, cc = (tid & 3) * 8;
                float4 v0 = *reinterpret_cast<const float4*>(&xs[r][cc]);
                float4 v1 = *reinterpret_cast<const float4*>(&xs[r][cc + 4]);
                uint4 p;
                p.x = (unsigned int)f2bf(v0.x) | ((unsigned int)f2bf(v0.y) << 16);
                p.y = (unsigned int)f2bf(v0.z) | ((unsigned int)f2bf(v0.w) << 16);
                p.z = (unsigned int)f2bf(v1.x) | ((unsigned int)f2bf(v1.y) << 16);
                p.w = (unsigned int)f2bf(v1.z) | ((unsigned int)f2bf(v1.w) << 16);
                *reinterpret_cast<uint4*>(&xb[(size_t)(t0 + r) * DIM + k0 + cc]) = p;
            }
#pragma unroll
            for (int kk4 = 0; kk4 < 8; kk4++) {
                float4 xv[4], wv[4];
#pragma unroll
                for (int i = 0; i < 4; i++)
                    xv[i] = *reinterpret_cast<const float4*>(&xs[tg + 16 * i][kk4 * 4]);
#pragma unroll
                for (int j = 0; j < 4; j++)
                    wv[j] = *reinterpret_cast<const float4*>(&wsm[eg + 16 * j][kk4 * 4]);
#pragma unroll
                for (int i = 0; i < 4; i++)
#pragma unroll
                    for (int j = 0; j < 4; j++) {
                        acc[i][j] = fmaf(xv[i].x, wv[j].x, acc[i][j]);
                        acc[i][j] = fmaf(xv[i].y, wv[j].y, acc[i][j]);
                        acc[i][j] = fmaf(xv[i].z, wv[j].z, acc[i][j]);
                        acc[i][j] = fmaf(xv[i].w, wv[j].w, acc[i][j]);
                    }
            }
        }
#pragma unroll
        for (int j = 0; j < 4; j++) {
            float b = gb[eg + 16 * j];
#pragma unroll
            for (int i = 0; i < 4; i++) acc[i][j] += b;
        }
#pragma unroll
        for (int i = 0; i < 4; i++) {
            float m1 = -1e30f, m2 = -1e30f; int e1 = 0;
#pragma unroll
            for (int j = 0; j < 4; j++) {
                float v = acc[i][j]; int e = eg + 16 * j;
                if (v > m1) { m2 = m1; m1 = v; e1 = e; }
                else if (v > m2) m2 = v;
            }
#pragma unroll
            for (int d = 1; d < 16; d <<= 1) {
                float om1 = __shfl_xor(m1, d, 16);
                float om2 = __shfl_xor(m2, d, 16);
                int   oe1 = __shfl_xor(e1, d, 16);
                if (om1 > m1 || (om1 == m1 && oe1 < e1)) {
                    m2 = fmaxf(om2, m1); m1 = om1; e1 = oe1;
                } else {
                    m2 = fmaxf(m2, om1);
                }
            }
            if (eg == 0) {
                int t = t0 + tg + 16 * i;
                sel[t] = e1;
                if (m1 - m2 < 1e-3f) {
                    int idx = atomicAdd(nflag, 1);
                    if (idx < 4096) flags[idx] = t;
                }
            }
        }
    } else {
        // ---------------- W transpose ----------------
        if (!wt) return;
        unsigned short (*ts)[68] = (unsigned short(*)[68])smem;
        int lin = blockIdx.x - 512;
        int e = lin >> 8;
        int d0 = (lin & 15) * 64, o0 = ((lin >> 4) & 15) * 64;
        const float* src = ew + (size_t)e * (DIM * OUTD);
        int r = tid >> 4, c = (tid & 15) * 4;
#pragma unroll
        for (int i = 0; i < 4; i++) {
            int rr = r + i * 16;
            float4 v = *reinterpret_cast<const float4*>(&src[(size_t)(d0 + rr) * OUTD + o0 + c]);
            ushort4 u;
            u.x = f2bf(v.x); u.y = f2bf(v.y); u.z = f2bf(v.z); u.w = f2bf(v.w);
            *reinterpret_cast<ushort4*>(&ts[rr][c]) = u;
        }
        __syncthreads();
        unsigned short* dst = wt + (size_t)e * (DIM * OUTD);
        int dc = tid & 7;
#pragma unroll
        for (int i = 0; i < 2; i++) {
            int oo = (tid >> 3) + i * 32;
            uint4 p;
            p.x = (unsigned int)ts[dc*8+0][oo] | ((unsigned int)ts[dc*8+1][oo] << 16);
            p.y = (unsigned int)ts[dc*8+2][oo] | ((unsigned int)ts[dc*8+3][oo] << 16);
            p.z = (unsigned int)ts[dc*8+4][oo] | ((unsigned int)ts[dc*8+5][oo] << 16);
            p.w = (unsigned int)ts[dc*8+6][oo] | ((unsigned int)ts[dc*8+7][oo] << 16);
            *reinterpret_cast<uint4*>(&dst[(size_t)(o0 + oo) * DIM + d0 + dc * 8]) = p;
        }
    }
}

__global__ __launch_bounds__(64) void gate_fix_kernel(const float* __restrict__ x,
        const float* __restrict__ gw, const float* __restrict__ gb,
        int* __restrict__ sel, const int* __restrict__ nflag, const int* __restrict__ flags)
{
    int n = *nflag; if (n > 4096) n = 4096;
    int b = blockIdx.x;
    if (b >= n) return;
    int t = flags[b];
    int e = threadIdx.x;
    const float* xr = x + (size_t)t * DIM;
    const float* wr = gw + (size_t)e * DIM;
    double acc = (double)gb[e];
    for (int k = 0; k < DIM; k += 4) {
        acc += (double)xr[k]   * (double)wr[k];
        acc += (double)xr[k+1] * (double)wr[k+1];
        acc += (double)xr[k+2] * (double)wr[k+2];
        acc += (double)xr[k+3] * (double)wr[k+3];
    }
    double m1 = acc; int e1 = e;
#pragma unroll
    for (int d = 1; d < 64; d <<= 1) {
        double om1 = __shfl_xor(m1, d, 64);
        int   oe1  = __shfl_xor(e1, d, 64);
        if (om1 > m1 || (om1 == m1 && oe1 < e1)) { m1 = om1; e1 = oe1; }
    }
    if (e == 0) sel[t] = e1;
}

__global__ __launch_bounds__(256) void hist_kernel(const int* __restrict__ sel,
                                                   int* __restrict__ counts)
{
    __shared__ int h[NEXP];
    int tid = threadIdx.x;
    if (tid < NEXP) h[tid] = 0;
    __syncthreads();
    int t = blockIdx.x * 256 + tid;
    atomicAdd(&h[sel[t]], 1);
    __syncthreads();
    if (tid < NEXP && h[tid]) atomicAdd(&counts[tid], h[tid]);
}

__global__ void sched_kernel(const int* __restrict__ counts, int* __restrict__ offsets,
                             int* __restrict__ schedE, int* __restrict__ schedR,
                             int* __restrict__ totalRB)
{
    if (threadIdx.x != 0) return;
    int off = 0, rb = 0;
    for (int e = 0; e < NEXP; e++) {
        int c = counts[e];
        offsets[e] = off;
        int nb = (c + 127) >> 7;
        for (int b2 = 0; b2 < nb; b2++) { schedE[rb] = e; schedR[rb] = b2 * 128; rb++; }
        off += c;
    }
    offsets[NEXP] = off;
    *totalRB = rb;
}

__global__ __launch_bounds__(256) void scatter_kernel(const int* __restrict__ sel,
        const int* __restrict__ offsets, int* __restrict__ cursor, int* __restrict__ perm)
{
    int t = blockIdx.x * 256 + threadIdx.x;
    int e = sel[t];
    int pos = offsets[e] + atomicAdd(&cursor[e], 1);
    perm[pos] = t;
}

// ---------------- grouped expert GEMM, 128x128x32 bf16 MFMA, 2-phase dbuf pipeline ----------------
// lin -> rb = lin>>3, cb = lin&7: round-robin XCD dispatch pins one output column per XCD
// (wt column slice L2-resident; same-expert rbs temporally adjacent).
// LDS k-chunk XOR swizzle (R2, proven 0-conflict): storage chunk s of row holds global
// chunk s ^ ((row>>1)&3); fragment read applies same XOR.
__global__ __launch_bounds__(256) void moe_gemm2(
        const unsigned short* __restrict__ xb, const unsigned short* __restrict__ wt,
        const float* __restrict__ eb,
        const int* __restrict__ perm, const int* __restrict__ offsets,
        const int* __restrict__ counts, const int* __restrict__ schedE,
        const int* __restrict__ schedR, const int* __restrict__ totalRB,
        float* __restrict__ out)
{
    int lin = blockIdx.x;
    int rb = lin >> 3, cb = lin & 7;
    if (rb >= *totalRB) return;
    int e = schedE[rb], r0 = schedR[rb];
    int cnt = counts[e], base = offsets[e];

    __shared__ __align__(16) unsigned short As[8192];   // 2 bufs x 128 x 32
    __shared__ __align__(16) unsigned short Bs[8192];
    __shared__ int toks[128];

    int tid = threadIdx.x;
    if (tid < 128) {
        int r = r0 + tid;
        toks[tid] = (r < cnt) ? perm[base + r] : -1;
    }
    __syncthreads();

    int lane = tid & 63;
    int wv = tid >> 6;
    int wr = wv >> 1, wc = wv & 1;
    int lr = lane & 15, lg = lane >> 4;

    int rowS = tid >> 2;
    int koff = (((tid & 3) ^ ((tid >> 3) & 3)) * 8);
    int tokA1 = toks[rowS];      if (tokA1 < 0) tokA1 = 0;
    int tokA2 = toks[64 + rowS]; if (tokA2 < 0) tokA2 = 0;

    const unsigned short* wte = wt + ((size_t)e << 20);
    const unsigned short* bSrc1 = wte + (size_t)(cb * 128 + rowS) * DIM + koff;
    const unsigned short* bSrc2 = wte + (size_t)(cb * 128 + 64 + rowS) * DIM + koff;
    const unsigned short* aSrc1 = xb + (size_t)tokA1 * DIM + koff;
    const unsigned short* aSrc2 = xb + (size_t)tokA2 * DIM + koff;

    unsigned short* AsW0 = As + wv * 512;          // wave-uniform bases (+lane*16B by HW)
    unsigned short* AsW1 = As + 2048 + wv * 512;
    unsigned short* BsW0 = Bs + wv * 512;
    unsigned short* BsW1 = Bs + 2048 + wv * 512;

    f32x4 acc[4][4];
#pragma unroll
    for (int m = 0; m < 4; m++)
#pragma unroll
        for (int n = 0; n < 4; n++)
#pragma unroll
            for (int c = 0; c < 4; c++) acc[m][n][c] = 0.f;

    const char* Asc = (const char*)As;
    const char* Bsc = (const char*)Bs;
    int fko = ((lg ^ ((lr >> 1) & 3)) * 16);

    auto stage = [&](int buf, int k0) {
        int off = buf * 4096;   // shorts
        GLOAD16(bSrc1 + k0, BsW0 + off);
        GLOAD16(bSrc2 + k0, BsW1 + off);
        GLOAD16(aSrc1 + k0, AsW0 + off);
        GLOAD16(aSrc2 + k0, AsW1 + off);
    };
    auto compute = [&](int buf) {
        int boff = buf * 8192;  // bytes
        bf16x8 bfr[4];
#pragma unroll
        for (int n = 0; n < 4; n++) {
            int row = wc * 64 + n * 16 + lr;
            bfr[n] = *reinterpret_cast<const bf16x8*>(Bsc + boff + (row << 6) + fko);
        }
#pragma unroll
        for (int m = 0; m < 4; m++) {
            int row = wr * 64 + m * 16 + lr;
            bf16x8 afr = *reinterpret_cast<const bf16x8*>(Asc + boff + (row << 6) + fko);
#pragma unroll
            for (int n = 0; n < 4; n++)
                acc[m][n] = __builtin_amdgcn_mfma_f32_16x16x32_bf16(afr, bfr[n], acc[m][n], 0, 0, 0);
        }
    };

    // prologue
    stage(0, 0);
    asm volatile("s_waitcnt vmcnt(0)" ::: "memory");
    __builtin_amdgcn_s_barrier();
    asm volatile("" ::: "memory");

    int cur = 0;
#pragma unroll 1
    for (int t = 0; t < 31; ++t) {
        stage(cur ^ 1, (t + 1) * 32);   // prefetch next tile (in flight across compute)
        compute(cur);
        asm volatile("s_waitcnt vmcnt(0)" ::: "memory");   // next tile landed
        __builtin_amdgcn_s_barrier();                       // all reads of cur done
        asm volatile("" ::: "memory");
        cur ^= 1;
    }
    compute(cur);

    // epilogue: C/D layout col = lane&15, row = (lane>>4)*4 + i
#pragma unroll
    for (int n = 0; n < 4; n++) {
        int oc = cb * 128 + wc * 64 + n * 16 + lr;
        float bias = eb[e * OUTD + oc];
#pragma unroll
        for (int m = 0; m < 4; m++) {
#pragma unroll
            for (int i2 = 0; i2 < 4; i2++) {
                int rr = wr * 64 + m * 16 + lg * 4 + i2;
                int tk = toks[rr];
                if (tk >= 0)
                    out[(size_t)tk * OUTD + oc] = acc[m][n][i2] + bias;
            }
        }
    }
}

// ---------------- legacy (R1) GEMM — fallback if ws too small ----------------
__global__ __launch_bounds__(256) void moe_gemm_legacy(const float* __restrict__ x,
        const float* __restrict__ ew, const float* __restrict__ eb,
        const int* __restrict__ perm, const int* __restrict__ offsets,
        const int* __restrict__ counts, const int* __restrict__ schedE,
        const int* __restrict__ schedR, const int* __restrict__ totalRB,
        float* __restrict__ out)
{
    int rb = blockIdx.x;
    if (rb >= *totalRB) return;
    int cb = blockIdx.y;
    int e = schedE[rb], r0 = schedR[rb];
    int cnt = counts[e], base = offsets[e];

    __shared__ __align__(16) unsigned short As[128][40];
    __shared__ __align__(16) unsigned short Bs[128][40];
    __shared__ int toks[128];

    int tid = threadIdx.x;
    if (tid < 128) {
        int r = r0 + tid;
        toks[tid] = (r < cnt) ? perm[base + r] : -1;
    }
    __syncthreads();

    int lane = tid & 63;
    int wave = tid >> 6;
    int wr = wave >> 1, wc = wave & 1;
    int lr = lane & 15, lg = lane >> 4;

    f32x4 acc[4][4];
#pragma unroll
    for (int m = 0; m < 4; m++)
#pragma unroll
        for (int n = 0; n < 4; n++)
#pragma unroll
            for (int c = 0; c < 4; c++) acc[m][n][c] = 0.f;

    int aRow[4]; int aTok[4];
#pragma unroll
    for (int q = 0; q < 4; q++) {
        aRow[q] = (tid >> 3) + q * 32;
        int tk = toks[aRow[q]];
        aTok[q] = (tk < 0) ? 0 : tk;
    }
    int ac4 = tid & 7;
    int d0 = (tid >> 5) * 4;
    int o_lane = tid & 31;
    const float* wb = ew + (size_t)e * (DIM * OUTD) + (size_t)cb * 128;

    for (int k0 = 0; k0 < DIM; k0 += 32) {
        float4 av[4];
#pragma unroll
        for (int q = 0; q < 4; q++)
            av[q] = *reinterpret_cast<const float4*>(&x[(size_t)aTok[q] * DIM + k0 + ac4 * 4]);
        float bv[4][4];
#pragma unroll
        for (int i2 = 0; i2 < 4; i2++)
#pragma unroll
            for (int j = 0; j < 4; j++)
                bv[i2][j] = wb[(size_t)(k0 + d0 + i2) * OUTD + o_lane + 32 * j];

        __syncthreads();
#pragma unroll
        for (int q = 0; q < 4; q++) {
            uint2 p;
            p.x = (unsigned int)f2bf(av[q].x) | ((unsigned int)f2bf(av[q].y) << 16);
            p.y = (unsigned int)f2bf(av[q].z) | ((unsigned int)f2bf(av[q].w) << 16);
            *reinterpret_cast<uint2*>(&As[aRow[q]][ac4 * 4]) = p;
        }
#pragma unroll
        for (int j = 0; j < 4; j++) {
            uint2 p;
            p.x = (unsigned int)f2bf(bv[0][j]) | ((unsigned int)f2bf(bv[1][j]) << 16);
            p.y = (unsigned int)f2bf(bv[2][j]) | ((unsigned int)f2bf(bv[3][j]) << 16);
            *reinterpret_cast<uint2*>(&Bs[o_lane + 32 * j][d0]) = p;
        }
        __syncthreads();

        bf16x8 bfr[4];
#pragma unroll
        for (int n = 0; n < 4; n++)
            bfr[n] = *reinterpret_cast<const bf16x8*>(&Bs[wc * 64 + n * 16 + lr][lg * 8]);
#pragma unroll
        for (int m = 0; m < 4; m++) {
            bf16x8 afr = *reinterpret_cast<const bf16x8*>(&As[wr * 64 + m * 16 + lr][lg * 8]);
#pragma unroll
            for (int n = 0; n < 4; n++)
                acc[m][n] = __builtin_amdgcn_mfma_f32_16x16x32_bf16(afr, bfr[n], acc[m][n], 0, 0, 0);
        }
    }

#pragma unroll
    for (int n = 0; n < 4; n++) {
        int oc = cb * 128 + wc * 64 + n * 16 + lr;
        float bias = eb[e * OUTD + oc];
#pragma unroll
        for (int m = 0; m < 4; m++) {
#pragma unroll
            for (int i2 = 0; i2 < 4; i2++) {
                int rr = wr * 64 + m * 16 + lg * 4 + i2;
                int tk = toks[rr];
                if (tk >= 0)
                    out[(size_t)tk * OUTD + oc] = acc[m][n][i2] + bias;
            }
        }
    }
}

extern "C" void kernel_launch(void* const* d_in, const int* in_sizes, int n_in,
                              void* d_out, int out_size, void* d_ws, size_t ws_size,
                              hipStream_t stream)
{
    const float* x  = (const float*)d_in[0];
    const float* gw = (const float*)d_in[1];
    const float* gb = (const float*)d_in[2];
    const float* ew = (const float*)d_in[3];
    const float* eb = (const float*)d_in[4];
    float* out = (float*)d_out;

    char* ws = (char*)d_ws;
    int* counts  = (int*)(ws + 0);
    int* cursor  = (int*)(ws + 256);
    int* offsets = (int*)(ws + 512);
    int* totalRB = (int*)(ws + 1024);
    int* nflag   = (int*)(ws + 1028);
    int* flags   = (int*)(ws + 1032);
    int* schedE  = (int*)(ws + 20480);
    int* schedR  = (int*)(ws + 22528);
    int* sel     = (int*)(ws + 24576);
    int* perm    = (int*)(ws + 155648);

    const size_t WT_OFF   = (size_t)1 << 20;
    const size_t WT_BYTES = (size_t)NEXP * DIM * OUTD * 2;   // 128 MiB
    const size_t XB_OFF   = WT_OFF + WT_BYTES;
    const size_t XB_BYTES = (size_t)N_TOK * DIM * 2;         // 64 MiB
    int mode = (ws_size >= XB_OFF + XB_BYTES) ? 2
             : (ws_size >= WT_OFF + WT_BYTES) ? 1 : 0;
    unsigned short* wt = (mode >= 1) ? (unsigned short*)(ws + WT_OFF) : nullptr;
    unsigned short* xb = (mode == 2) ? (unsigned short*)(ws + XB_OFF) : nullptr;

    hipMemsetAsync(ws, 0, 2048, stream);

    // gate (512 blocks) + W transpose (16384 blocks) fused, overlapping on the machine
    prep_kernel<<<dim3(512 + ((mode >= 1) ? 16384 : 0)), 256, 0, stream>>>(
        x, gw, gb, ew, sel, nflag, flags, xb, wt);
    gate_fix_kernel<<<dim3(4096), 64, 0, stream>>>(x, gw, gb, sel, nflag, flags);
    hist_kernel<<<dim3(N_TOK / 256), 256, 0, stream>>>(sel, counts);
    sched_kernel<<<dim3(1), 64, 0, stream>>>(counts, offsets, schedE, schedR, totalRB);
    scatter_kernel<<<dim3(N_TOK / 256), 256, 0, stream>>>(sel, offsets, cursor, perm);

    if (mode == 2)
        moe_gemm2<<<dim3(2560), 256, 0, stream>>>(xb, wt, eb, perm, offsets, counts,
                                                  schedE, schedR, totalRB, out);
    else
        moe_gemm_legacy<<<dim3(320, 8), 256, 0, stream>>>(x, ew, eb, perm, offsets, counts,
                                                          schedE, schedR, totalRB, out);
}